// Round 2
// baseline (5344.460 us; speedup 1.0000x reference)
//
#include <hip/hip_runtime.h>
#include <hip/hip_bf16.h>

#define T_ 512
#define B_ 64
#define OBS_ 512
#define H_ 1024
#define A_ 18
#define MM_ (T_*B_)   // 32768
#define G4_ (4*H_)    // 4096
#define CH_ 64        // time steps per chunk
#define NCH_ (T_/CH_) // 8 chunks
#define CM_ (CH_*B_)  // 4096 rows per chunk

typedef unsigned short u16;
typedef __attribute__((ext_vector_type(8))) short s8v;
typedef __attribute__((ext_vector_type(4))) float f4v;

__device__ __forceinline__ float b2f(u16 u){
    unsigned x = ((unsigned)u) << 16;
    return __builtin_bit_cast(float, x);
}
__device__ __forceinline__ u16 f2b(float f){
    unsigned x = __builtin_bit_cast(unsigned, f);
    return (u16)((x + 0x7fffu + ((x >> 16) & 1u)) >> 16);  // RNE
}

// ---------------- small utility kernels ----------------

__global__ void cast_f32_bf16(const float* __restrict__ in, u16* __restrict__ out, int n){
    int i = blockIdx.x * blockDim.x + threadIdx.x;
    int stride = gridDim.x * blockDim.x;
    for (; i < n; i += stride) out[i] = f2b(in[i]);
}

__global__ void add_bias2(const float* __restrict__ a, const float* __restrict__ b,
                          float* __restrict__ out, int n){
    int i = blockIdx.x * blockDim.x + threadIdx.x;
    if (i < n) out[i] = a[i] + b[i];
}

__global__ void zero_init(u16* __restrict__ hping, float* __restrict__ c, int n){
    int i = blockIdx.x * blockDim.x + threadIdx.x;
    if (i < n){ hping[i] = 0; c[i] = 0.f; }
}

__global__ void copy_hc(const float* __restrict__ h, const float* __restrict__ c,
                        float* __restrict__ out){
    int i = blockIdx.x * blockDim.x + threadIdx.x;  // 65536 threads
    out[(size_t)MM_*A_ + i] = h[i];
    out[(size_t)MM_*A_ + B_*H_ + i] = c[i];
}

// ---------------- bf16 MFMA GEMM: C = act(A @ W^T + bias), W is (N,K) ----------------
// 128x128 tile, BK=64, 256 threads = 4 waves in 2x2, each wave 4x4 16x16 MFMA tiles.

#define LDSS 72  // 64 + 8 pad (stride 144 B -> 2-way LDS aliasing only, free)

template<bool A_FP32, bool RELU>
__global__ __launch_bounds__(256) void gemm_bt(
    const void* __restrict__ Aptr, const u16* __restrict__ W,
    const float* __restrict__ bias, u16* __restrict__ C,
    int M, int N, int K)
{
    __shared__ __align__(16) u16 As[128 * LDSS];
    __shared__ __align__(16) u16 Bs[128 * LDSS];

    const int tid  = threadIdx.x;
    const int lane = tid & 63;
    const int wid  = tid >> 6;
    const int wm   = wid & 1, wn = wid >> 1;
    const int m0   = blockIdx.y * 128, n0 = blockIdx.x * 128;
    const int quad = lane >> 4, l16 = lane & 15;

    f4v acc[4][4];
    #pragma unroll
    for (int i = 0; i < 4; i++)
        #pragma unroll
        for (int j = 0; j < 4; j++) acc[i][j] = (f4v){0.f,0.f,0.f,0.f};

    for (int k0 = 0; k0 < K; k0 += 64){
        __syncthreads();
        if (A_FP32){
            const float* A = (const float*)Aptr;
            #pragma unroll
            for (int pss = 0; pss < 8; pss++){
                int idx = pss * 256 + tid;
                int row = idx >> 4, ch = idx & 15;
                float4 v = *(const float4*)(A + (size_t)(m0 + row) * K + k0 + ch * 4);
                u16* d = &As[row * LDSS + ch * 4];
                d[0] = f2b(v.x); d[1] = f2b(v.y); d[2] = f2b(v.z); d[3] = f2b(v.w);
            }
        } else {
            const u16* A = (const u16*)Aptr;
            #pragma unroll
            for (int pss = 0; pss < 4; pss++){
                int idx = pss * 256 + tid;
                int row = idx >> 3, ch = idx & 7;
                *(uint4*)&As[row * LDSS + ch * 8] =
                    *(const uint4*)(A + (size_t)(m0 + row) * K + k0 + ch * 8);
            }
        }
        #pragma unroll
        for (int pss = 0; pss < 4; pss++){
            int idx = pss * 256 + tid;
            int row = idx >> 3, ch = idx & 7;
            *(uint4*)&Bs[row * LDSS + ch * 8] =
                *(const uint4*)(W + (size_t)(n0 + row) * K + k0 + ch * 8);
        }
        __syncthreads();

        #pragma unroll
        for (int kk = 0; kk < 64; kk += 32){
            s8v af[4], bf[4];
            #pragma unroll
            for (int mt = 0; mt < 4; mt++)
                af[mt] = *(const s8v*)&As[(wm*64 + mt*16 + l16) * LDSS + kk + quad*8];
            #pragma unroll
            for (int nt = 0; nt < 4; nt++)
                bf[nt] = *(const s8v*)&Bs[(wn*64 + nt*16 + l16) * LDSS + kk + quad*8];
            #pragma unroll
            for (int mt = 0; mt < 4; mt++)
                #pragma unroll
                for (int nt = 0; nt < 4; nt++)
                    acc[mt][nt] = __builtin_amdgcn_mfma_f32_16x16x32_bf16(
                        af[mt], bf[nt], acc[mt][nt], 0, 0, 0);
        }
    }

    // epilogue: C/D layout col = lane&15, row = quad*4 + r  [learn_hip m89]
    #pragma unroll
    for (int mt = 0; mt < 4; mt++){
        #pragma unroll
        for (int nt = 0; nt < 4; nt++){
            #pragma unroll
            for (int r = 0; r < 4; r++){
                int m = m0 + wm*64 + mt*16 + quad*4 + r;
                int n = n0 + wn*64 + nt*16 + l16;
                float v = acc[mt][nt][r] + bias[n];
                if (RELU) v = fmaxf(v, 0.f);
                C[(size_t)m * N + n] = f2b(v);
            }
        }
    }
}

// ---------------- LSTM step: 256 blocks x 4 hidden units each ----------------
// gates(64 x 16) = h(64 x 1024) @ Whh_slice(16 x 1024)^T, K split over 4 waves.

__global__ __launch_bounds__(256) void lstm_step(
    const u16* __restrict__ xg,      // [64][4096] bf16 (t applied)
    const u16* __restrict__ Whh,     // [4096][1024] bf16
    const u16* __restrict__ h_src,   // [64][1024] bf16
    u16* __restrict__ h_dst,
    float* __restrict__ c,           // [64][1024] fp32 persistent
    float* __restrict__ h_f32,
    u16* __restrict__ latent_t,      // [64][1024] bf16
    const float* __restrict__ mask_t)
{
    __shared__ float red[4][64][16];

    const int tid  = threadIdx.x;
    const int lane = tid & 63;
    const int w    = tid >> 6;
    const int quad = lane >> 4, l16 = lane & 15;
    const int j0   = blockIdx.x * 4;

    // lane's B-row: n = l16 -> gate = n>>2, unit = n&3
    const int gate = l16 >> 2, un = l16 & 3;
    const u16* wrow = Whh + (size_t)(gate * H_ + j0 + un) * H_;

    f4v acc[4];
    #pragma unroll
    for (int mt = 0; mt < 4; mt++) acc[mt] = (f4v){0.f,0.f,0.f,0.f};

    const int kbase = w * 256;
    #pragma unroll
    for (int ki = 0; ki < 8; ki++){
        int k = kbase + ki * 32 + quad * 8;
        s8v bfrag = *(const s8v*)(wrow + k);
        #pragma unroll
        for (int mt = 0; mt < 4; mt++){
            s8v afrag = *(const s8v*)(h_src + (size_t)(mt*16 + l16) * H_ + k);
            acc[mt] = __builtin_amdgcn_mfma_f32_16x16x32_bf16(afrag, bfrag, acc[mt], 0,0,0);
        }
    }
    #pragma unroll
    for (int mt = 0; mt < 4; mt++)
        #pragma unroll
        for (int r = 0; r < 4; r++)
            red[w][mt*16 + quad*4 + r][l16] = acc[mt][r];
    __syncthreads();

    // cell update: thread -> (b = tid>>2, u = tid&3)
    const int b = tid >> 2, uu = tid & 3;
    float gi = 0.f, gf = 0.f, gg = 0.f, go = 0.f;
    #pragma unroll
    for (int ww = 0; ww < 4; ww++){
        gi += red[ww][b][ 0 + uu];
        gf += red[ww][b][ 4 + uu];
        gg += red[ww][b][ 8 + uu];
        go += red[ww][b][12 + uu];
    }
    gi += b2f(xg[b * G4_ + 0*H_ + j0 + uu]);
    gf += b2f(xg[b * G4_ + 1*H_ + j0 + uu]);
    gg += b2f(xg[b * G4_ + 2*H_ + j0 + uu]);
    go += b2f(xg[b * G4_ + 3*H_ + j0 + uu]);

    float is = 1.f / (1.f + __expf(-gi));
    float fs = 1.f / (1.f + __expf(-gf));
    float os = 1.f / (1.f + __expf(-go));
    float gt = tanhf(gg);

    const int ci = b * H_ + j0 + uu;
    float cn = fs * c[ci] + is * gt;
    float hn = os * tanhf(cn);
    float m = mask_t[b];
    hn *= m; cn *= m;
    c[ci] = cn;
    h_f32[ci] = hn;
    u16 hb = f2b(hn);
    h_dst[ci] = hb;
    latent_t[ci] = hb;
}

// ---------------- decode: values = (latent @ Wdec^T + bdec) * mask ----------------

__global__ __launch_bounds__(256) void decode_kernel(
    const u16* __restrict__ latent, const u16* __restrict__ Wdec,
    const float* __restrict__ bdec, const float* __restrict__ mask,
    float* __restrict__ values, int rows)
{
    __shared__ __align__(16) u16 wl[A_ * H_];
    const int tid = threadIdx.x;
    for (int i = tid; i < A_ * H_ / 8; i += 256)
        ((uint4*)wl)[i] = ((const uint4*)Wdec)[i];
    __syncthreads();

    const int lane = tid & 63;
    int wid = blockIdx.x * 4 + (tid >> 6);
    const int nwaves = gridDim.x * 4;

    for (int row = wid; row < rows; row += nwaves){
        float lat[16];
        #pragma unroll
        for (int i = 0; i < 16; i++)
            lat[i] = b2f(latent[(size_t)row * H_ + i*64 + lane]);
        float acc[A_];
        #pragma unroll
        for (int a = 0; a < A_; a++) acc[a] = 0.f;
        #pragma unroll
        for (int i = 0; i < 16; i++){
            #pragma unroll
            for (int a = 0; a < A_; a++)
                acc[a] += lat[i] * b2f(wl[a * H_ + i*64 + lane]);
        }
        float m = mask[row];
        #pragma unroll
        for (int a = 0; a < A_; a++){
            float v = acc[a];
            #pragma unroll
            for (int s = 32; s > 0; s >>= 1) v += __shfl_down(v, s, 64);
            if (lane == 0) values[(size_t)row * A_ + a] = (v + bdec[a]) * m;
        }
    }
}

// ---------------- launcher ----------------

extern "C" void kernel_launch(void* const* d_in, const int* in_sizes, int n_in,
                              void* d_out, int out_size, void* d_ws, size_t ws_size,
                              hipStream_t stream)
{
    const float* obs  = (const float*)d_in[0];
    const float* mask = (const float*)d_in[1];
    const float* Wenc = (const float*)d_in[2];
    const float* benc = (const float*)d_in[3];
    const float* Wih  = (const float*)d_in[4];
    const float* bih  = (const float*)d_in[5];
    const float* Whh  = (const float*)d_in[6];
    const float* bhh  = (const float*)d_in[7];
    const float* Wdec = (const float*)d_in[8];
    const float* bdec = (const float*)d_in[9];
    float* out = (float*)d_out;

    // chunked workspace: ~66 MB total (fits modest ws_size; round-0's 421 MB
    // monolithic layout is the suspected cause of the memory-fault abort)
    char* p = (char*)d_ws;
    size_t o = 0;
    auto alloc = [&](size_t bytes){ void* r = p + o; o += (bytes + 255) & ~(size_t)255; return r; };
    u16*   wenc_b  = (u16*)  alloc((size_t)H_ * OBS_ * 2);      // 1 MB
    u16*   wih_b   = (u16*)  alloc((size_t)G4_ * H_ * 2);       // 8 MB
    u16*   whh_b   = (u16*)  alloc((size_t)G4_ * H_ * 2);       // 8 MB
    u16*   wdec_b  = (u16*)  alloc((size_t)A_ * H_ * 2);        // 36 KB
    float* bias2   = (float*)alloc((size_t)G4_ * 4);            // 16 KB
    u16*   enc_ch  = (u16*)  alloc((size_t)CM_ * H_ * 2);       // 8 MB
    u16*   xg_ch   = (u16*)  alloc((size_t)CM_ * G4_ * 2);      // 32 MB
    u16*   lat_ch  = (u16*)  alloc((size_t)CM_ * H_ * 2);       // 8 MB
    u16*   h_ping  = (u16*)  alloc((size_t)B_ * H_ * 2);
    u16*   h_pong  = (u16*)  alloc((size_t)B_ * H_ * 2);
    float* h_f32   = (float*)alloc((size_t)B_ * H_ * 4);
    float* c_f32   = (float*)alloc((size_t)B_ * H_ * 4);
    (void)ws_size; (void)in_sizes; (void)n_in; (void)out_size;

    // weight casts + bias combine + state init
    cast_f32_bf16<<<1024, 256, 0, stream>>>(Wenc, wenc_b, H_ * OBS_);
    cast_f32_bf16<<<2048, 256, 0, stream>>>(Wih,  wih_b,  G4_ * H_);
    cast_f32_bf16<<<2048, 256, 0, stream>>>(Whh,  whh_b,  G4_ * H_);
    cast_f32_bf16<<<72,   256, 0, stream>>>(Wdec, wdec_b, A_ * H_);
    add_bias2<<<16, 256, 0, stream>>>(bih, bhh, bias2, G4_);
    zero_init<<<256, 256, 0, stream>>>(h_ping, c_f32, B_ * H_);

    u16* hbuf[2] = { h_ping, h_pong };
    int parity = 0;

    for (int c = 0; c < NCH_; c++){
        const int t0 = c * CH_;

        // GEMM1 chunk: enc = relu(obs[t0:t0+CH] @ Wenc^T + benc), M=4096 N=1024 K=512
        dim3 g1(H_ / 128, CM_ / 128);
        gemm_bt<true, true><<<g1, 256, 0, stream>>>(
            obs + (size_t)t0 * B_ * OBS_, wenc_b, benc, enc_ch, CM_, H_, OBS_);

        // GEMM2 chunk: xg = enc @ Wih^T + (bih+bhh), M=4096 N=4096 K=1024
        dim3 g2(G4_ / 128, CM_ / 128);
        gemm_bt<false, false><<<g2, 256, 0, stream>>>(
            enc_ch, wih_b, bias2, xg_ch, CM_, G4_, H_);

        // sequential scan within chunk
        for (int s = 0; s < CH_; s++){
            lstm_step<<<256, 256, 0, stream>>>(
                xg_ch + (size_t)s * B_ * G4_, whh_b,
                hbuf[parity], hbuf[parity ^ 1],
                c_f32, h_f32,
                lat_ch + (size_t)s * B_ * H_,
                mask + (size_t)(t0 + s) * B_);
            parity ^= 1;
        }

        // decode chunk
        decode_kernel<<<256, 256, 0, stream>>>(
            lat_ch, wdec_b, bdec, mask + (size_t)t0 * B_,
            out + (size_t)t0 * B_ * A_, CM_);
    }

    copy_hc<<<256, 256, 0, stream>>>(h_f32, c_f32, out);
}